// Round 14
// baseline (57.919 us; speedup 1.0000x reference)
//
#include <hip/hip_runtime.h>
#include <hip/hip_fp16.h>

#define N_ 16
#define C_ 128
#define S_ 16384
#define K_ 64

typedef __attribute__((ext_vector_type(4))) float f32x4;
typedef __attribute__((ext_vector_type(8))) _Float16 f16x8;
typedef __attribute__((ext_vector_type(4))) _Float16 f16x4;

// f16-granule row swizzle (xT, W)
#define SWZ_S(s) ((((s) ^ ((s) >> 3)) & 7) << 3)
#define SWZ16(k) (((k) & 7) << 3)
// fp8 rows are 64 B; byte-granule XOR swizzle
#define SWZ8(r) (((r) & 7) << 3)

// pack 4 f32 -> 4 fp8 e4m3 bytes (OCP on gfx950)
static __device__ __forceinline__ unsigned int pack_fp8x4(float a, float b,
                                                          float c, float d) {
    int v = __builtin_amdgcn_cvt_pk_fp8_f32(a, b, 0, false);
    v = __builtin_amdgcn_cvt_pk_fp8_f32(c, d, v, true);
    return (unsigned int)v;
}

// ---------------------------------------------------------------------------
// Fused v11 = v10 with (a) f16 partial slabs (halve slab traffic; partials
// are O(1)-magnitude, f16 noise ~1e-4 at output vs 4.17e-4 threshold) and
// (b) prefetch issued immediately after `pre` is consumed (before norms +
// softmax) so the loads get the whole softmax+S2 window to land.
// ---------------------------------------------------------------------------
__global__ __launch_bounds__(256, 3) void fused_kernel(
    const float* __restrict__ x, const float* __restrict__ fc_w,
    const float* __restrict__ fc_b, __half* __restrict__ vlad_part,
    float* __restrict__ a_part)
{
    __shared__ __align__(16) _Float16 xT[64 * 128];            // 16 KB [s][c]
    __shared__ __align__(16) _Float16 Wlds[64 * 128];          // 16 KB [k][c]
    __shared__ __align__(16) unsigned char xC8[2][128 * 64];   // 16 KB [c][s] fp8
    __shared__ __align__(16) unsigned char sst8[64 * 64];      //  4 KB [k][s] fp8 (P*256)
    __shared__ float rns[2][64];                               // 512 B

    const int tid = threadIdx.x;
    const int lane = tid & 63, w = tid >> 6;
    const int lr = lane & 15, g = lane >> 4;
    const int fsw8 = SWZ8(lr);     // fp8 rows of form m*16+lr
    const int fsw16 = SWZ16(lr);   // f16 rows of form m*16+lr

    // block -> (n, tile range, slab slot); 6-tilers are blocks 0..255
    const int b = blockIdx.x;
    const int n     = (b < 256) ? (b >> 4) : ((b - 256) >> 5);
    const int lo    = (b < 256) ? (b & 15) * 6 : 96 + ((b - 256) & 31) * 5;
    const int cnt   = (b < 256) ? 6 : 5;
    const int jslot = (b < 256) ? (b & 15) : 16 + ((b - 256) & 31);
    const int sl    = n * 48 + jslot;

    // ---- stage W once into LDS (f16, swizzled) ----
#pragma unroll
    for (int i = 0; i < 8; ++i) {
        int idx = i * 256 + tid;
        int c4 = idx & 31, k = idx >> 5;
        float4 wv = *(const float4*)(fc_w + k * C_ + c4 * 4);
        f16x4 hi = {(_Float16)wv.x, (_Float16)wv.y, (_Float16)wv.z, (_Float16)wv.w};
        *(f16x4*)&Wlds[k * 128 + ((c4 * 4) ^ SWZ16(k))] = hi;
    }
    if (tid < 128) (&rns[0][0])[tid] = 0.f;

    float bias[4];
#pragma unroll
    for (int nt = 0; nt < 4; ++nt) bias[nt] = fc_b[nt * 16 + lr];
    float a_acc[4] = {0.f, 0.f, 0.f, 0.f};
    f32x4 vacc[8];
#pragma unroll
    for (int nt = 0; nt < 8; ++nt) vacc[nt] = (f32x4){0.f, 0.f, 0.f, 0.f};
    f32x4 accp[4];   // logits(i) carried S2(i) -> S1(i+1)

    const float* xb = x + (size_t)n * C_ * S_;
    const int s4 = tid & 15;
    int cqv[2];
#pragma unroll
    for (int i = 0; i < 2; ++i) cqv[i] = i * 16 + (tid >> 4);

    // prefetch first tile
    float4 pre[2][4];
#pragma unroll
    for (int i = 0; i < 2; ++i)
#pragma unroll
        for (int cc = 0; cc < 4; ++cc)
            pre[i][cc] = *(const float4*)(xb + (size_t)(cqv[i] * 4 + cc) * S_ +
                                          lo * 64 + s4 * 4);

    auto softmax_emit = [&](int pit) {
        float rnl[4], ai[4];
#pragma unroll
        for (int r = 0; r < 4; ++r)
            rnl[r] = 1.0f / fmaxf(sqrtf(rns[pit][w * 16 + g * 4 + r]), 1e-12f);
        if (lane < 16) rns[pit][w * 16 + lane] = 0.f;  // same-wave DS order: safe
#pragma unroll
        for (int nt = 0; nt < 4; ++nt)
#pragma unroll
            for (int r = 0; r < 4; ++r)
                accp[nt][r] = __expf(accp[nt][r] * rnl[r] + bias[nt]);
#pragma unroll
        for (int r = 0; r < 4; ++r) {
            float sum = (accp[0][r] + accp[1][r]) + (accp[2][r] + accp[3][r]);
            sum += __shfl_xor(sum, 1);
            sum += __shfl_xor(sum, 2);
            sum += __shfl_xor(sum, 4);
            sum += __shfl_xor(sum, 8);
            float bi = 1.0f / sum;
            ai[r] = bi * rnl[r] * 256.0f;   // P' scaled x256 for fp8 range
#pragma unroll
            for (int nt = 0; nt < 4; ++nt) a_acc[nt] += accp[nt][r] * bi;
        }
#pragma unroll
        for (int nt = 0; nt < 4; ++nt) {
            int k = nt * 16 + lr;
            int sloc = w * 16 + g * 4;
            unsigned int pk = pack_fp8x4(accp[nt][0] * ai[0], accp[nt][1] * ai[1],
                                         accp[nt][2] * ai[2], accp[nt][3] * ai[3]);
            *(unsigned int*)&sst8[k * 64 + (sloc ^ SWZ8(k))] = pk;
        }
    };

#pragma unroll 1
    for (int it = 0; it < cnt; ++it) {
        const int bb = it & 1;
        __syncthreads();   // top: xT/sst8 consumed (S2(it-1)); xC8[bb] free

        // ---- S1: stage tile it (consumes pre) ----
        float part[4] = {0.f, 0.f, 0.f, 0.f};
#pragma unroll
        for (int i = 0; i < 2; ++i) {
            int cq = cqv[i];
#pragma unroll
            for (int jj = 0; jj < 4; ++jj) {
                float v0 = (&pre[i][0].x)[jj], v1 = (&pre[i][1].x)[jj],
                      v2 = (&pre[i][2].x)[jj], v3 = (&pre[i][3].x)[jj];
                part[jj] += v0 * v0 + v1 * v1 + v2 * v2 + v3 * v3;
                f16x4 p = {(_Float16)v0, (_Float16)v1, (_Float16)v2, (_Float16)v3};
                int s = s4 * 4 + jj;
                *(f16x4*)&xT[s * 128 + ((cq * 4) ^ SWZ_S(s))] = p;
            }
#pragma unroll
            for (int cc = 0; cc < 4; ++cc) {
                int c = cq * 4 + cc;
                unsigned int pk = pack_fp8x4(pre[i][cc].x, pre[i][cc].y,
                                             pre[i][cc].z, pre[i][cc].w);
                *(unsigned int*)&xC8[bb][c * 64 + ((s4 * 4) ^ SWZ8(c))] = pk;
            }
        }
        // prefetch tile it+1 IMMEDIATELY (pre is dead now; loads get the
        // norms+softmax+S2 window to land)
        if (it + 1 < cnt) {
            const float* xb2 = xb + (lo + it + 1) * 64;
#pragma unroll
            for (int i = 0; i < 2; ++i)
#pragma unroll
                for (int cc = 0; cc < 4; ++cc)
                    pre[i][cc] = *(const float4*)(xb2 + (size_t)(cqv[i] * 4 + cc) * S_ + s4 * 4);
        }
#pragma unroll
        for (int jj = 0; jj < 4; ++jj) {
            part[jj] += __shfl_xor(part[jj], 16);
            part[jj] += __shfl_xor(part[jj], 32);
        }
        if (g == 0) {
#pragma unroll
            for (int jj = 0; jj < 4; ++jj)
                atomicAdd(&rns[it & 1][lr * 4 + jj], part[jj]);
        }
        if (it > 0) softmax_emit((it - 1) & 1);
        __syncthreads();   // xT/xC8[bb]/sst8/rns visible

        // ---- S2: pure MFMA + LDS reads ----
#pragma unroll
        for (int nt = 0; nt < 4; ++nt) accp[nt] = (f32x4){0.f, 0.f, 0.f, 0.f};
        __builtin_amdgcn_s_setprio(1);
#pragma unroll
        for (int kt = 0; kt < 4; ++kt) {
            const int co = kt * 32 + g * 8;
            const int sa = w * 16 + lr;
            f16x8 af = *(const f16x8*)&xT[sa * 128 + (co ^ SWZ_S(sa))];
#pragma unroll
            for (int nt = 0; nt < 4; ++nt) {
                f16x8 wf = *(const f16x8*)&Wlds[(nt * 16 + lr) * 128 + (co ^ fsw16)];
                accp[nt] = __builtin_amdgcn_mfma_f32_16x16x32_f16(af, wf, accp[nt], 0, 0, 0);
            }
        }
        if (it > 0) {
            const unsigned char* xcp = xC8[bb ^ 1];
#pragma unroll
            for (int kt = 0; kt < 2; ++kt) {
                const int so = kt * 32 + g * 8;
                long pa = *(const long*)&sst8[(w * 16 + lr) * 64 + (so ^ fsw8)];
#pragma unroll
                for (int nt = 0; nt < 8; ++nt) {
                    long xv = *(const long*)&xcp[(nt * 16 + lr) * 64 + (so ^ fsw8)];
                    vacc[nt] = __builtin_amdgcn_mfma_f32_16x16x32_fp8_fp8(pa, xv, vacc[nt], 0, 0, 0);
                }
            }
        }
        __builtin_amdgcn_s_setprio(0);
    }

    // ---- epilogue: softmax(cnt-1) -> sst8, then vlad(cnt-1) ----
    const int lastb = (cnt - 1) & 1;
    __syncthreads();
    softmax_emit(lastb);
    __syncthreads();
    {
        const unsigned char* xcp = xC8[lastb];
#pragma unroll
        for (int kt = 0; kt < 2; ++kt) {
            const int so = kt * 32 + g * 8;
            long pa = *(const long*)&sst8[(w * 16 + lr) * 64 + (so ^ fsw8)];
#pragma unroll
            for (int nt = 0; nt < 8; ++nt) {
                long xv = *(const long*)&xcp[(nt * 16 + lr) * 64 + (so ^ fsw8)];
                vacc[nt] = __builtin_amdgcn_mfma_f32_16x16x32_fp8_fp8(pa, xv, vacc[nt], 0, 0, 0);
            }
        }
    }

    // ---- flush: f16 stores to this block's slab (unscale /256) ----
    __half* vp = vlad_part + (size_t)sl * (K_ * C_) + (w * 16) * C_;
#pragma unroll
    for (int nt = 0; nt < 8; ++nt)
#pragma unroll
        for (int r = 0; r < 4; ++r)
            vp[(g * 4 + r) * C_ + nt * 16 + lr] =
                __float2half(vacc[nt][r] * (1.0f / 256.0f));
#pragma unroll
    for (int nt = 0; nt < 4; ++nt) {
        a_acc[nt] += __shfl_xor(a_acc[nt], 16);
        a_acc[nt] += __shfl_xor(a_acc[nt], 32);
    }
    if (lane < 16) {
#pragma unroll
        for (int nt = 0; nt < 4; ++nt)
            a_part[sl * 256 + w * 64 + nt * 16 + lr] = a_acc[nt];
    }
}

// ---------------------------------------------------------------------------
// Finalize v2 (reduce fused in): thread t owns k = t>>4, c = (t&15)*8 .. +8
// (contiguous -> f16x8 slab loads coalesce perfectly). Sums 48 slabs, then
// a_sum reduce, -a*cent, intra-norm (shfl over the 16-lane k-group), global
// norm, f32 output as 2x float4.
// ---------------------------------------------------------------------------
__global__ __launch_bounds__(1024) void finalize_kernel(
    const __half* __restrict__ vlad_part, const float* __restrict__ a_part,
    const float* __restrict__ centroids, float* __restrict__ out)
{
    __shared__ float red[16];
    const int n = blockIdx.x;
    const int t = threadIdx.x;
    const int k = t >> 4, q = t & 15;
    const int c0 = q * 8;

    // sum 48 slabs (f16x8 per load, fully coalesced)
    float vsum[8] = {0.f, 0.f, 0.f, 0.f, 0.f, 0.f, 0.f, 0.f};
    {
        const __half* p = vlad_part + (size_t)(n * 48) * (K_ * C_) + k * C_ + c0;
#pragma unroll 4
        for (int slb = 0; slb < 48; ++slb) {
            f16x8 v = *(const f16x8*)(p + (size_t)slb * (K_ * C_));
#pragma unroll
            for (int jj = 0; jj < 8; ++jj) vsum[jj] += (float)v[jj];
        }
    }

    // a_sum[k]: 48 chunks x 4 waves; q handles chunks q*3..q*3+2
    float av = 0.f;
#pragma unroll
    for (int cc = 0; cc < 3; ++cc) {
        int ch = q * 3 + cc;
        const float* ap = a_part + (size_t)(n * 48 + ch) * 256 + k;
#pragma unroll
        for (int ww = 0; ww < 4; ++ww) av += ap[ww * 64];
    }
    av += __shfl_xor(av, 1);
    av += __shfl_xor(av, 2);
    av += __shfl_xor(av, 4);
    av += __shfl_xor(av, 8);

    const float* cp = centroids + k * C_ + c0;
    float4 cpa = *(const float4*)cp;
    float4 cpb = *(const float4*)(cp + 4);
    float v[8];
    float ssq = 0.f;
#pragma unroll
    for (int jj = 0; jj < 8; ++jj) {
        float cv = (jj < 4) ? (&cpa.x)[jj] : (&cpb.x)[jj - 4];
        float val = vsum[jj] - av * cv;
        v[jj] = val;
        ssq += val * val;
    }
    ssq += __shfl_xor(ssq, 1);
    ssq += __shfl_xor(ssq, 2);
    ssq += __shfl_xor(ssq, 4);
    ssq += __shfl_xor(ssq, 8);
    const float inv1 = 1.0f / fmaxf(sqrtf(ssq), 1e-12f);

    float gp = (q == 0) ? ssq * inv1 * inv1 : 0.f;
#pragma unroll
    for (int off = 1; off < 64; off <<= 1) gp += __shfl_xor(gp, off);
    if ((t & 63) == 0) red[t >> 6] = gp;
    __syncthreads();
    float G = 0.f;
#pragma unroll
    for (int i = 0; i < 16; ++i) G += red[i];
    const float ginv = 1.0f / fmaxf(sqrtf(G), 1e-12f);

    float* op = out + (size_t)n * (K_ * C_) + k * C_ + c0;
    float4 oa, ob;
#pragma unroll
    for (int jj = 0; jj < 4; ++jj) {
        (&oa.x)[jj] = v[jj] * inv1 * ginv;
        (&ob.x)[jj] = v[jj + 4] * inv1 * ginv;
    }
    *(float4*)op = oa;
    *(float4*)(op + 4) = ob;
}

extern "C" void kernel_launch(void* const* d_in, const int* in_sizes, int n_in,
                              void* d_out, int out_size, void* d_ws, size_t ws_size,
                              hipStream_t stream) {
    const float* x     = (const float*)d_in[0];
    const float* fc_w  = (const float*)d_in[1];
    const float* fc_b  = (const float*)d_in[2];
    const float* cent  = (const float*)d_in[3];
    float* out = (float*)d_out;

    char* ws = (char*)d_ws;
    __half* vlad_part = (__half*)ws;                                  // 12.6 MB
    float* a_part     = (float*)(ws + (size_t)768 * K_ * C_ * 2);     // 768 KB

    fused_kernel<<<768, 256, 0, stream>>>(x, fc_w, fc_b, vlad_part, a_part);
    finalize_kernel<<<N_, 1024, 0, stream>>>(vlad_part, a_part, cent, out);
}

// Round 15
// 53.007 us; speedup vs baseline: 1.0927x; 1.0927x over previous
//
#include <hip/hip_runtime.h>
#include <hip/hip_fp16.h>

#define N_ 16
#define C_ 128
#define S_ 16384
#define K_ 64

typedef __attribute__((ext_vector_type(4))) float f32x4;
typedef __attribute__((ext_vector_type(8))) _Float16 f16x8;
typedef __attribute__((ext_vector_type(4))) _Float16 f16x4;

// f16-granule row swizzle (xT, W)
#define SWZ_S(s) ((((s) ^ ((s) >> 3)) & 7) << 3)
#define SWZ16(k) (((k) & 7) << 3)
// fp8 rows are 64 B; byte-granule XOR swizzle
#define SWZ8(r) (((r) & 7) << 3)

// pack 4 f32 -> 4 fp8 e4m3 bytes (OCP on gfx950)
static __device__ __forceinline__ unsigned int pack_fp8x4(float a, float b,
                                                          float c, float d) {
    int v = __builtin_amdgcn_cvt_pk_fp8_f32(a, b, 0, false);
    v = __builtin_amdgcn_cvt_pk_fp8_f32(c, d, v, true);
    return (unsigned int)v;
}

// ---------------------------------------------------------------------------
// Fused v12 = v11 with the prefetch back in r13's slot (after softmax_emit):
// issuing it early extended pre's live range across softmax under the 84-reg
// cap and spilled (r14: FETCH +2.7MB, +6us). Keeps f16 slabs + fused finalize.
// ---------------------------------------------------------------------------
__global__ __launch_bounds__(256, 3) void fused_kernel(
    const float* __restrict__ x, const float* __restrict__ fc_w,
    const float* __restrict__ fc_b, __half* __restrict__ vlad_part,
    float* __restrict__ a_part)
{
    __shared__ __align__(16) _Float16 xT[64 * 128];            // 16 KB [s][c]
    __shared__ __align__(16) _Float16 Wlds[64 * 128];          // 16 KB [k][c]
    __shared__ __align__(16) unsigned char xC8[2][128 * 64];   // 16 KB [c][s] fp8
    __shared__ __align__(16) unsigned char sst8[64 * 64];      //  4 KB [k][s] fp8 (P*256)
    __shared__ float rns[2][64];                               // 512 B

    const int tid = threadIdx.x;
    const int lane = tid & 63, w = tid >> 6;
    const int lr = lane & 15, g = lane >> 4;
    const int fsw8 = SWZ8(lr);     // fp8 rows of form m*16+lr
    const int fsw16 = SWZ16(lr);   // f16 rows of form m*16+lr

    // block -> (n, tile range, slab slot); 6-tilers are blocks 0..255
    const int b = blockIdx.x;
    const int n     = (b < 256) ? (b >> 4) : ((b - 256) >> 5);
    const int lo    = (b < 256) ? (b & 15) * 6 : 96 + ((b - 256) & 31) * 5;
    const int cnt   = (b < 256) ? 6 : 5;
    const int jslot = (b < 256) ? (b & 15) : 16 + ((b - 256) & 31);
    const int sl    = n * 48 + jslot;

    // ---- stage W once into LDS (f16, swizzled) ----
#pragma unroll
    for (int i = 0; i < 8; ++i) {
        int idx = i * 256 + tid;
        int c4 = idx & 31, k = idx >> 5;
        float4 wv = *(const float4*)(fc_w + k * C_ + c4 * 4);
        f16x4 hi = {(_Float16)wv.x, (_Float16)wv.y, (_Float16)wv.z, (_Float16)wv.w};
        *(f16x4*)&Wlds[k * 128 + ((c4 * 4) ^ SWZ16(k))] = hi;
    }
    if (tid < 128) (&rns[0][0])[tid] = 0.f;

    float bias[4];
#pragma unroll
    for (int nt = 0; nt < 4; ++nt) bias[nt] = fc_b[nt * 16 + lr];
    float a_acc[4] = {0.f, 0.f, 0.f, 0.f};
    f32x4 vacc[8];
#pragma unroll
    for (int nt = 0; nt < 8; ++nt) vacc[nt] = (f32x4){0.f, 0.f, 0.f, 0.f};
    f32x4 accp[4];   // logits(i) carried S2(i) -> S1(i+1)

    const float* xb = x + (size_t)n * C_ * S_;
    const int s4 = tid & 15;
    int cqv[2];
#pragma unroll
    for (int i = 0; i < 2; ++i) cqv[i] = i * 16 + (tid >> 4);

    // prefetch first tile
    float4 pre[2][4];
#pragma unroll
    for (int i = 0; i < 2; ++i)
#pragma unroll
        for (int cc = 0; cc < 4; ++cc)
            pre[i][cc] = *(const float4*)(xb + (size_t)(cqv[i] * 4 + cc) * S_ +
                                          lo * 64 + s4 * 4);

    auto softmax_emit = [&](int pit) {
        float rnl[4], ai[4];
#pragma unroll
        for (int r = 0; r < 4; ++r)
            rnl[r] = 1.0f / fmaxf(sqrtf(rns[pit][w * 16 + g * 4 + r]), 1e-12f);
        if (lane < 16) rns[pit][w * 16 + lane] = 0.f;  // same-wave DS order: safe
#pragma unroll
        for (int nt = 0; nt < 4; ++nt)
#pragma unroll
            for (int r = 0; r < 4; ++r)
                accp[nt][r] = __expf(accp[nt][r] * rnl[r] + bias[nt]);
#pragma unroll
        for (int r = 0; r < 4; ++r) {
            float sum = (accp[0][r] + accp[1][r]) + (accp[2][r] + accp[3][r]);
            sum += __shfl_xor(sum, 1);
            sum += __shfl_xor(sum, 2);
            sum += __shfl_xor(sum, 4);
            sum += __shfl_xor(sum, 8);
            float bi = 1.0f / sum;
            ai[r] = bi * rnl[r] * 256.0f;   // P' scaled x256 for fp8 range
#pragma unroll
            for (int nt = 0; nt < 4; ++nt) a_acc[nt] += accp[nt][r] * bi;
        }
#pragma unroll
        for (int nt = 0; nt < 4; ++nt) {
            int k = nt * 16 + lr;
            int sloc = w * 16 + g * 4;
            unsigned int pk = pack_fp8x4(accp[nt][0] * ai[0], accp[nt][1] * ai[1],
                                         accp[nt][2] * ai[2], accp[nt][3] * ai[3]);
            *(unsigned int*)&sst8[k * 64 + (sloc ^ SWZ8(k))] = pk;
        }
    };

#pragma unroll 1
    for (int it = 0; it < cnt; ++it) {
        const int bb = it & 1;
        __syncthreads();   // top: xT/sst8 consumed (S2(it-1)); xC8[bb] free

        // ---- S1: stage tile it ----
        float part[4] = {0.f, 0.f, 0.f, 0.f};
#pragma unroll
        for (int i = 0; i < 2; ++i) {
            int cq = cqv[i];
#pragma unroll
            for (int jj = 0; jj < 4; ++jj) {
                float v0 = (&pre[i][0].x)[jj], v1 = (&pre[i][1].x)[jj],
                      v2 = (&pre[i][2].x)[jj], v3 = (&pre[i][3].x)[jj];
                part[jj] += v0 * v0 + v1 * v1 + v2 * v2 + v3 * v3;
                f16x4 p = {(_Float16)v0, (_Float16)v1, (_Float16)v2, (_Float16)v3};
                int s = s4 * 4 + jj;
                *(f16x4*)&xT[s * 128 + ((cq * 4) ^ SWZ_S(s))] = p;
            }
#pragma unroll
            for (int cc = 0; cc < 4; ++cc) {
                int c = cq * 4 + cc;
                unsigned int pk = pack_fp8x4(pre[i][cc].x, pre[i][cc].y,
                                             pre[i][cc].z, pre[i][cc].w);
                *(unsigned int*)&xC8[bb][c * 64 + ((s4 * 4) ^ SWZ8(c))] = pk;
            }
        }
#pragma unroll
        for (int jj = 0; jj < 4; ++jj) {
            part[jj] += __shfl_xor(part[jj], 16);
            part[jj] += __shfl_xor(part[jj], 32);
        }
        if (g == 0) {
#pragma unroll
            for (int jj = 0; jj < 4; ++jj)
                atomicAdd(&rns[it & 1][lr * 4 + jj], part[jj]);
        }
        if (it > 0) softmax_emit((it - 1) & 1);
        // prefetch tile it+1 (r13 placement: after softmax, disjoint live range)
        if (it + 1 < cnt) {
            const float* xb2 = xb + (lo + it + 1) * 64;
#pragma unroll
            for (int i = 0; i < 2; ++i)
#pragma unroll
                for (int cc = 0; cc < 4; ++cc)
                    pre[i][cc] = *(const float4*)(xb2 + (size_t)(cqv[i] * 4 + cc) * S_ + s4 * 4);
        }
        __syncthreads();   // xT/xC8[bb]/sst8/rns visible

        // ---- S2: pure MFMA + LDS reads ----
#pragma unroll
        for (int nt = 0; nt < 4; ++nt) accp[nt] = (f32x4){0.f, 0.f, 0.f, 0.f};
        __builtin_amdgcn_s_setprio(1);
#pragma unroll
        for (int kt = 0; kt < 4; ++kt) {
            const int co = kt * 32 + g * 8;
            const int sa = w * 16 + lr;
            f16x8 af = *(const f16x8*)&xT[sa * 128 + (co ^ SWZ_S(sa))];
#pragma unroll
            for (int nt = 0; nt < 4; ++nt) {
                f16x8 wf = *(const f16x8*)&Wlds[(nt * 16 + lr) * 128 + (co ^ fsw16)];
                accp[nt] = __builtin_amdgcn_mfma_f32_16x16x32_f16(af, wf, accp[nt], 0, 0, 0);
            }
        }
        if (it > 0) {
            const unsigned char* xcp = xC8[bb ^ 1];
#pragma unroll
            for (int kt = 0; kt < 2; ++kt) {
                const int so = kt * 32 + g * 8;
                long pa = *(const long*)&sst8[(w * 16 + lr) * 64 + (so ^ fsw8)];
#pragma unroll
                for (int nt = 0; nt < 8; ++nt) {
                    long xv = *(const long*)&xcp[(nt * 16 + lr) * 64 + (so ^ fsw8)];
                    vacc[nt] = __builtin_amdgcn_mfma_f32_16x16x32_fp8_fp8(pa, xv, vacc[nt], 0, 0, 0);
                }
            }
        }
        __builtin_amdgcn_s_setprio(0);
    }

    // ---- epilogue: softmax(cnt-1) -> sst8, then vlad(cnt-1) ----
    const int lastb = (cnt - 1) & 1;
    __syncthreads();
    softmax_emit(lastb);
    __syncthreads();
    {
        const unsigned char* xcp = xC8[lastb];
#pragma unroll
        for (int kt = 0; kt < 2; ++kt) {
            const int so = kt * 32 + g * 8;
            long pa = *(const long*)&sst8[(w * 16 + lr) * 64 + (so ^ fsw8)];
#pragma unroll
            for (int nt = 0; nt < 8; ++nt) {
                long xv = *(const long*)&xcp[(nt * 16 + lr) * 64 + (so ^ fsw8)];
                vacc[nt] = __builtin_amdgcn_mfma_f32_16x16x32_fp8_fp8(pa, xv, vacc[nt], 0, 0, 0);
            }
        }
    }

    // ---- flush: f16 stores to this block's slab (unscale /256) ----
    __half* vp = vlad_part + (size_t)sl * (K_ * C_) + (w * 16) * C_;
#pragma unroll
    for (int nt = 0; nt < 8; ++nt)
#pragma unroll
        for (int r = 0; r < 4; ++r)
            vp[(g * 4 + r) * C_ + nt * 16 + lr] =
                __float2half(vacc[nt][r] * (1.0f / 256.0f));
#pragma unroll
    for (int nt = 0; nt < 4; ++nt) {
        a_acc[nt] += __shfl_xor(a_acc[nt], 16);
        a_acc[nt] += __shfl_xor(a_acc[nt], 32);
    }
    if (lane < 16) {
#pragma unroll
        for (int nt = 0; nt < 4; ++nt)
            a_part[sl * 256 + w * 64 + nt * 16 + lr] = a_acc[nt];
    }
}

// ---------------------------------------------------------------------------
// Finalize v2 (reduce fused in): thread t owns k = t>>4, c = (t&15)*8 .. +8
// (contiguous -> f16x8 slab loads coalesce perfectly). Sums 48 slabs, then
// a_sum reduce, -a*cent, intra-norm, global norm, f32 output as 2x float4.
// ---------------------------------------------------------------------------
__global__ __launch_bounds__(1024) void finalize_kernel(
    const __half* __restrict__ vlad_part, const float* __restrict__ a_part,
    const float* __restrict__ centroids, float* __restrict__ out)
{
    __shared__ float red[16];
    const int n = blockIdx.x;
    const int t = threadIdx.x;
    const int k = t >> 4, q = t & 15;
    const int c0 = q * 8;

    // sum 48 slabs (f16x8 per load, fully coalesced)
    float vsum[8] = {0.f, 0.f, 0.f, 0.f, 0.f, 0.f, 0.f, 0.f};
    {
        const __half* p = vlad_part + (size_t)(n * 48) * (K_ * C_) + k * C_ + c0;
#pragma unroll 4
        for (int slb = 0; slb < 48; ++slb) {
            f16x8 v = *(const f16x8*)(p + (size_t)slb * (K_ * C_));
#pragma unroll
            for (int jj = 0; jj < 8; ++jj) vsum[jj] += (float)v[jj];
        }
    }

    // a_sum[k]: 48 chunks x 4 waves; q handles chunks q*3..q*3+2
    float av = 0.f;
#pragma unroll
    for (int cc = 0; cc < 3; ++cc) {
        int ch = q * 3 + cc;
        const float* ap = a_part + (size_t)(n * 48 + ch) * 256 + k;
#pragma unroll
        for (int ww = 0; ww < 4; ++ww) av += ap[ww * 64];
    }
    av += __shfl_xor(av, 1);
    av += __shfl_xor(av, 2);
    av += __shfl_xor(av, 4);
    av += __shfl_xor(av, 8);

    const float* cp = centroids + k * C_ + c0;
    float4 cpa = *(const float4*)cp;
    float4 cpb = *(const float4*)(cp + 4);
    float v[8];
    float ssq = 0.f;
#pragma unroll
    for (int jj = 0; jj < 8; ++jj) {
        float cv = (jj < 4) ? (&cpa.x)[jj] : (&cpb.x)[jj - 4];
        float val = vsum[jj] - av * cv;
        v[jj] = val;
        ssq += val * val;
    }
    ssq += __shfl_xor(ssq, 1);
    ssq += __shfl_xor(ssq, 2);
    ssq += __shfl_xor(ssq, 4);
    ssq += __shfl_xor(ssq, 8);
    const float inv1 = 1.0f / fmaxf(sqrtf(ssq), 1e-12f);

    float gp = (q == 0) ? ssq * inv1 * inv1 : 0.f;
#pragma unroll
    for (int off = 1; off < 64; off <<= 1) gp += __shfl_xor(gp, off);
    if ((t & 63) == 0) red[t >> 6] = gp;
    __syncthreads();
    float G = 0.f;
#pragma unroll
    for (int i = 0; i < 16; ++i) G += red[i];
    const float ginv = 1.0f / fmaxf(sqrtf(G), 1e-12f);

    float* op = out + (size_t)n * (K_ * C_) + k * C_ + c0;
    float4 oa, ob;
#pragma unroll
    for (int jj = 0; jj < 4; ++jj) {
        (&oa.x)[jj] = v[jj] * inv1 * ginv;
        (&ob.x)[jj] = v[jj + 4] * inv1 * ginv;
    }
    *(float4*)op = oa;
    *(float4*)(op + 4) = ob;
}

extern "C" void kernel_launch(void* const* d_in, const int* in_sizes, int n_in,
                              void* d_out, int out_size, void* d_ws, size_t ws_size,
                              hipStream_t stream) {
    const float* x     = (const float*)d_in[0];
    const float* fc_w  = (const float*)d_in[1];
    const float* fc_b  = (const float*)d_in[2];
    const float* cent  = (const float*)d_in[3];
    float* out = (float*)d_out;

    char* ws = (char*)d_ws;
    __half* vlad_part = (__half*)ws;                                  // 12.6 MB
    float* a_part     = (float*)(ws + (size_t)768 * K_ * C_ * 2);     // 768 KB

    fused_kernel<<<768, 256, 0, stream>>>(x, fc_w, fc_b, vlad_part, a_part);
    finalize_kernel<<<N_, 1024, 0, stream>>>(vlad_part, a_part, cent, out);
}